// Round 1
// baseline (903.873 us; speedup 1.0000x reference)
//
#include <hip/hip_runtime.h>

constexpr int S    = 4096;   // sequence length
constexpr int NR   = 4093;   // S - 3 output rows
constexpr int KAPP = 10000;  // app inner dim
constexpr int EAPP = 256;    // app embedding dim
constexpr int ETIM = 64;     // tim embedding dim
constexpr int DIN  = 320;    // EAPP + ETIM
constexpr int NDEC = 10000;  // decoder output dim

// ---------------------------------------------------------------- embeddings
__global__ __launch_bounds__(256) void k_embed_tim(
    const int* __restrict__ tim, const float* __restrict__ emb_tim,
    float* __restrict__ x)
{
    int r = blockIdx.x * 4 + (threadIdx.x >> 6);
    int e = threadIdx.x & 63;
    x[(size_t)r * DIN + EAPP + e] = emb_tim[tim[r] * ETIM + e];
}

__global__ __launch_bounds__(256) void k_embed_ptim(
    const int* __restrict__ ptim, const float* __restrict__ emb_tim,
    float* __restrict__ y)
{
    int r = blockIdx.x * 4 + (threadIdx.x >> 6);
    int e = threadIdx.x & 63;
    if (r < NR) y[(size_t)r * DIN + EAPP + e] = emb_tim[ptim[r] * ETIM + e];
}

// ------------------------------------------------- per-row attention score s
__global__ __launch_bounds__(256) void k_score(
    const float* __restrict__ x, const float* __restrict__ W,
    float* __restrict__ s)
{
    int wave = threadIdx.x >> 6, lane = threadIdx.x & 63;
    int m = blockIdx.x * 4 + wave;
    float sum = 0.f;
    for (int k = lane; k < DIN; k += 64) sum += x[(size_t)m * DIN + k] * W[k];
    #pragma unroll
    for (int off = 32; off; off >>= 1) sum += __shfl_down(sum, off);
    if (lane == 0) s[m] = sum;
}

// ------------------------------------------- windowed softmax-ish pooling
__global__ void k_pooled(
    const float* __restrict__ x, const float* __restrict__ s,
    const float* __restrict__ attn_b, float* __restrict__ pooled)
{
    int n = blockIdx.x;          // 0..NR-1
    int d = threadIdx.x;         // 0..319
    float h[4];
    float den = 0.f;
    #pragma unroll
    for (int f = 0; f < 4; ++f) {
        h[f] = tanhf(s[n + f] + attn_b[f]);
        den += fabsf(h[f]);
    }
    float inv = 1.f / den;
    float p = 0.f;
    #pragma unroll
    for (int f = 0; f < 4; ++f)
        p = fmaf(h[f] * inv, x[(size_t)(n + f) * DIN + d], p);
    pooled[(size_t)n * DIN + d] = p;
}

// ------------------------------------------------------------- GEMM (NN)
// C[0:4096, bn:bn+64) (ld DIN) = A[4096 x KAPP] @ B[KAPP x EAPP]
__global__ __launch_bounds__(256) void k_gemm_app(
    const float* __restrict__ A, const float* __restrict__ B,
    float* __restrict__ C)
{
    __shared__ float As[32][64];
    __shared__ float Bs[32][64];
    const int tid = threadIdx.x;
    const int tx = tid & 15, ty = tid >> 4;
    const int bm = blockIdx.y << 6, bn = blockIdx.x << 6;

    auto ldA = [&](int kt, int it) {
        int f = tid + (it << 8);
        int m = f >> 3, k4 = (f & 7) << 2;
        float4 v = make_float4(0.f, 0.f, 0.f, 0.f);
        if (kt + k4 < KAPP)
            v = *(const float4*)(A + (size_t)(bm + m) * KAPP + kt + k4);
        return v;
    };
    auto ldB = [&](int kt, int it) {
        int f = tid + (it << 8);
        int k = f >> 4, j4 = (f & 15) << 2;
        float4 v = make_float4(0.f, 0.f, 0.f, 0.f);
        if (kt + k < KAPP)
            v = *(const float4*)(B + (size_t)(kt + k) * EAPP + bn + j4);
        return v;
    };
    auto stA = [&](int it, float4 v) {
        int f = tid + (it << 8);
        int m = f >> 3, k4 = (f & 7) << 2;
        As[k4 + 0][m] = v.x; As[k4 + 1][m] = v.y;
        As[k4 + 2][m] = v.z; As[k4 + 3][m] = v.w;
    };
    auto stB = [&](int it, float4 v) {
        int f = tid + (it << 8);
        int k = f >> 4, j4 = (f & 15) << 2;
        *(float4*)&Bs[k][j4] = v;
    };

    float acc[4][4] = {};
    float4 ra[2], rb[2];
    ra[0] = ldA(0, 0); ra[1] = ldA(0, 1);
    rb[0] = ldB(0, 0); rb[1] = ldB(0, 1);
    stA(0, ra[0]); stA(1, ra[1]); stB(0, rb[0]); stB(1, rb[1]);
    __syncthreads();

    for (int kt = 32; kt < KAPP + 32; kt += 32) {
        const bool nxt = kt < KAPP;
        if (nxt) {
            ra[0] = ldA(kt, 0); ra[1] = ldA(kt, 1);
            rb[0] = ldB(kt, 0); rb[1] = ldB(kt, 1);
        }
        #pragma unroll
        for (int k = 0; k < 32; ++k) {
            float4 a4 = *(const float4*)&As[k][ty << 2];
            float4 b4 = *(const float4*)&Bs[k][tx << 2];
            const float av[4] = {a4.x, a4.y, a4.z, a4.w};
            const float bv[4] = {b4.x, b4.y, b4.z, b4.w};
            #pragma unroll
            for (int i = 0; i < 4; ++i)
                #pragma unroll
                for (int j = 0; j < 4; ++j)
                    acc[i][j] = fmaf(av[i], bv[j], acc[i][j]);
        }
        if (nxt) {
            __syncthreads();
            stA(0, ra[0]); stA(1, ra[1]); stB(0, rb[0]); stB(1, rb[1]);
            __syncthreads();
        }
    }
    #pragma unroll
    for (int i = 0; i < 4; ++i) {
        float4 v = make_float4(acc[i][0], acc[i][1], acc[i][2], acc[i][3]);
        *(float4*)(C + (size_t)(bm + (ty << 2) + i) * DIN + bn + (tx << 2)) = v;
    }
}

// ------------------------------------------------------------- GEMM (NT)
// C[m, j] = epilogue( sum_k A[m,k] * B[j,k] )
// EPI 1: (acc + bias[j]) * emb_uid[uid[0]*EAPP + j]   (fc layer)
// EPI 2: sigmoid(acc + bias[j])                        (decoder)
template<int EPI>
__global__ __launch_bounds__(256) void k_gemm_nt(
    const float* __restrict__ A, int lda, int M,
    const float* __restrict__ B, int ldb, int Nb,
    const float* __restrict__ bias,
    const float* __restrict__ emb_uid, const int* __restrict__ uid,
    float* __restrict__ C, int ldc, int K)
{
    __shared__ float As[32][64];
    __shared__ float Bs[32][64];
    const int tid = threadIdx.x;
    const int tx = tid & 15, ty = tid >> 4;
    const int bm = blockIdx.y << 6, bn = blockIdx.x << 6;

    auto ldA = [&](int kt, int it) {
        int f = tid + (it << 8);
        int m = f >> 3, k4 = (f & 7) << 2;
        // rows bm+m <= 4095 are always inside the 4096-row ws buffers
        return *(const float4*)(A + (size_t)(bm + m) * lda + kt + k4);
    };
    auto ldB = [&](int kt, int it) {
        int f = tid + (it << 8);
        int jr = f >> 3, k4 = (f & 7) << 2;
        float4 v = make_float4(0.f, 0.f, 0.f, 0.f);
        if (bn + jr < Nb)
            v = *(const float4*)(B + (size_t)(bn + jr) * ldb + kt + k4);
        return v;
    };
    auto stA = [&](int it, float4 v) {
        int f = tid + (it << 8);
        int m = f >> 3, k4 = (f & 7) << 2;
        As[k4 + 0][m] = v.x; As[k4 + 1][m] = v.y;
        As[k4 + 2][m] = v.z; As[k4 + 3][m] = v.w;
    };
    auto stB = [&](int it, float4 v) {
        int f = tid + (it << 8);
        int jr = f >> 3, k4 = (f & 7) << 2;
        Bs[k4 + 0][jr] = v.x; Bs[k4 + 1][jr] = v.y;
        Bs[k4 + 2][jr] = v.z; Bs[k4 + 3][jr] = v.w;
    };

    float acc[4][4] = {};
    float4 ra[2], rb[2];
    ra[0] = ldA(0, 0); ra[1] = ldA(0, 1);
    rb[0] = ldB(0, 0); rb[1] = ldB(0, 1);
    stA(0, ra[0]); stA(1, ra[1]); stB(0, rb[0]); stB(1, rb[1]);
    __syncthreads();

    for (int kt = 32; kt < K + 32; kt += 32) {
        const bool nxt = kt < K;
        if (nxt) {
            ra[0] = ldA(kt, 0); ra[1] = ldA(kt, 1);
            rb[0] = ldB(kt, 0); rb[1] = ldB(kt, 1);
        }
        #pragma unroll
        for (int k = 0; k < 32; ++k) {
            float4 a4 = *(const float4*)&As[k][ty << 2];
            float4 b4 = *(const float4*)&Bs[k][tx << 2];
            const float av[4] = {a4.x, a4.y, a4.z, a4.w};
            const float bv[4] = {b4.x, b4.y, b4.z, b4.w};
            #pragma unroll
            for (int i = 0; i < 4; ++i)
                #pragma unroll
                for (int j = 0; j < 4; ++j)
                    acc[i][j] = fmaf(av[i], bv[j], acc[i][j]);
        }
        if (nxt) {
            __syncthreads();
            stA(0, ra[0]); stA(1, ra[1]); stB(0, rb[0]); stB(1, rb[1]);
            __syncthreads();
        }
    }

    const float* us = (EPI == 1) ? (emb_uid + (size_t)uid[0] * EAPP) : nullptr;
    #pragma unroll
    for (int i = 0; i < 4; ++i) {
        int row = bm + (ty << 2) + i;
        if (row >= M) continue;
        #pragma unroll
        for (int j = 0; j < 4; ++j) {
            int col = bn + (tx << 2) + j;
            if (col >= Nb) continue;
            float v = acc[i][j] + bias[col];
            if (EPI == 1) v *= us[col];
            else          v = 1.f / (1.f + __expf(-v));
            C[(size_t)row * ldc + col] = v;
        }
    }
}

// ---------------------------------------------------------------- launcher
extern "C" void kernel_launch(void* const* d_in, const int* in_sizes, int n_in,
                              void* d_out, int out_size, void* d_ws, size_t ws_size,
                              hipStream_t stream)
{
    const int*   tim       = (const int*)  d_in[0];
    const float* app       = (const float*)d_in[1];
    // d_in[2] = loc (unused by the reference)
    const int*   uid       = (const int*)  d_in[3];
    const int*   ptim      = (const int*)  d_in[4];
    const float* emb_tim_w = (const float*)d_in[5];
    const float* emb_uid_w = (const float*)d_in[6];
    const float* emb_app_w = (const float*)d_in[7];
    const float* attn_W    = (const float*)d_in[8];
    const float* attn_b    = (const float*)d_in[9];
    const float* attn_fc_w = (const float*)d_in[10];
    const float* attn_fc_b = (const float*)d_in[11];
    const float* dec_w     = (const float*)d_in[12];
    const float* dec_b     = (const float*)d_in[13];
    float* out = (float*)d_out;

    float* ws     = (float*)d_ws;
    float* x      = ws;                        // [4096][320]; reused as y later
    float* pooled = ws + (size_t)S * DIN;      // [4096][320] (rows 0..4092 used)
    float* s      = ws + (size_t)2 * S * DIN;  // [4096]

    // x[:, 256:320] = emb_tim_w[tim]
    k_embed_tim<<<S / 4, 256, 0, stream>>>(tim, emb_tim_w, x);
    // x[:, 0:256] = app @ emb_app_w
    dim3 gApp(EAPP / 64, S / 64);
    k_gemm_app<<<gApp, 256, 0, stream>>>(app, emb_app_w, x);
    // s[m] = x[m] . attn_W
    k_score<<<S / 4, 256, 0, stream>>>(x, attn_W, s);
    // pooled[n] = sum_f Xn[n,f] * x[n+f]
    k_pooled<<<NR, DIN, 0, stream>>>(x, s, attn_b, pooled);
    // y[:, 256:320] = emb_tim_w[ptim]   (x buffer becomes y; x fully consumed)
    k_embed_ptim<<<(NR + 3) / 4, 256, 0, stream>>>(ptim, emb_tim_w, x);
    // y[:, 0:256] = (pooled @ attn_fc_w.T + fc_b) * uid_emb
    dim3 gFc(EAPP / 64, (NR + 63) / 64);
    k_gemm_nt<1><<<gFc, 256, 0, stream>>>(pooled, DIN, NR, attn_fc_w, DIN, EAPP,
                                          attn_fc_b, emb_uid_w, uid,
                                          x, DIN, DIN);
    // score = sigmoid(y @ dec_w.T + dec_b)
    dim3 gDec((NDEC + 63) / 64, (NR + 63) / 64);
    k_gemm_nt<2><<<gDec, 256, 0, stream>>>(x, DIN, NR, dec_w, DIN, NDEC,
                                           dec_b, nullptr, nullptr,
                                           out, NDEC, DIN);
}

// Round 2
// 241.194 us; speedup vs baseline: 3.7475x; 3.7475x over previous
//
#include <hip/hip_runtime.h>

typedef __attribute__((ext_vector_type(8))) short  bf16x8;   // 8 bf16 = 4 VGPR
typedef __attribute__((ext_vector_type(8))) unsigned short u16x8;
typedef __attribute__((ext_vector_type(4))) float  f32x4;

constexpr int S    = 4096;
constexpr int NR   = 4093;
constexpr int KAPP = 10000;
constexpr int KPAD = 10112;  // 4*2528, covers padded split-K range
constexpr int EAPP = 256;
constexpr int ETIM = 64;
constexpr int DIN  = 320;
constexpr int NDEC = 10000;
constexpr int LDP  = 40;     // LDS row stride (32 k + 8 pad) in bf16 elems

__device__ inline unsigned short f2bf(float f) {
    unsigned u = __float_as_uint(f);
    u += 0x7fffu + ((u >> 16) & 1u);      // RTN-even
    return (unsigned short)(u >> 16);
}
__device__ inline float bf2f(unsigned short h) {
    return __uint_as_float(((unsigned)h) << 16);
}
__device__ inline u16x8 pack8(f32x4 a, f32x4 b) {
    u16x8 v;
    v[0]=f2bf(a.x); v[1]=f2bf(a.y); v[2]=f2bf(a.z); v[3]=f2bf(a.w);
    v[4]=f2bf(b.x); v[5]=f2bf(b.y); v[6]=f2bf(b.z); v[7]=f2bf(b.w);
    return v;
}

// -------------------------------------------------- fp32 -> bf16 bulk convert
__global__ __launch_bounds__(256) void k_cvt_bf16(
    const float* __restrict__ in, unsigned short* __restrict__ out, int n8)
{
    int id = blockIdx.x * 256 + threadIdx.x;
    if (id >= n8) return;
    const float* p = in + (size_t)id * 8;
    f32x4 a = *reinterpret_cast<const f32x4*>(p);
    f32x4 b = *reinterpret_cast<const f32x4*>(p + 4);
    *reinterpret_cast<u16x8*>(out + (size_t)id * 8) = pack8(a, b);
}

// ------------------------------- emb_app_w [10000][256] -> Bp bf16 [256][10112]
__global__ __launch_bounds__(256) void k_transpose_appw(
    const float* __restrict__ B, unsigned short* __restrict__ Bp)
{
    __shared__ float T[64][68];
    const int kt = blockIdx.x * 64, nt = blockIdx.y * 64;
    const int tid = threadIdx.x;
    #pragma unroll
    for (int i = 0; i < 4; ++i) {
        int c = tid + (i << 8);
        int k = c >> 4, n4 = (c & 15) << 2;
        f32x4 v = {0.f, 0.f, 0.f, 0.f};
        if (kt + k < KAPP)
            v = *reinterpret_cast<const f32x4*>(&B[(size_t)(kt + k) * EAPP + nt + n4]);
        *reinterpret_cast<f32x4*>(&T[k][n4]) = v;
    }
    __syncthreads();
    #pragma unroll
    for (int i = 0; i < 2; ++i) {
        int c = tid + (i << 8);
        int n = c >> 3, ko = (c & 7) << 3;
        u16x8 v;
        #pragma unroll
        for (int j = 0; j < 8; ++j) v[j] = f2bf(T[ko + j][n]);
        *reinterpret_cast<u16x8*>(&Bp[(size_t)(nt + n) * KPAD + kt + ko]) = v;
    }
}

// ---------------------------------------------------------------- embeddings
__global__ __launch_bounds__(256) void k_embed_tim(
    const int* __restrict__ tim, const float* __restrict__ emb_tim,
    unsigned short* __restrict__ xb)
{
    int r = blockIdx.x * 4 + (threadIdx.x >> 6);
    int e = threadIdx.x & 63;
    xb[(size_t)r * DIN + EAPP + e] = f2bf(emb_tim[tim[r] * ETIM + e]);
}
__global__ __launch_bounds__(256) void k_embed_ptim(
    const int* __restrict__ ptim, const float* __restrict__ emb_tim,
    unsigned short* __restrict__ yb)
{
    int r = blockIdx.x * 4 + (threadIdx.x >> 6);
    int e = threadIdx.x & 63;
    if (r < NR) yb[(size_t)r * DIN + EAPP + e] = f2bf(emb_tim[ptim[r] * ETIM + e]);
}

// ---------------------------------------------- app GEMM: split-K x4, MFMA
// part[ks][4096][256] += app[64 rows][2528 k] @ Bp^T    (tile 64x256)
__global__ __launch_bounds__(256) void k_gemm_app_mfma(
    const float* __restrict__ A, const unsigned short* __restrict__ Bp,
    float* __restrict__ part)
{
    __shared__ unsigned short As[2][64 * LDP];
    __shared__ unsigned short Bs[2][256 * LDP];
    const int tid = threadIdx.x;
    const int lane = tid & 63, w = tid >> 6;
    const int ks = blockIdx.x;           // k-slice 0..3
    const int bm = blockIdx.y << 6;      // 64-row block
    const int k0 = ks * 2528;

    u16x8 ra, rb[4];
    auto gload = [&](int kt) {           // kt = absolute k of this step
        {
            int row = tid >> 2, ko = (tid & 3) << 3;
            int k = kt + ko;
            u16x8 v = {0,0,0,0,0,0,0,0};
            if (k < KAPP) {
                const float* p = &A[(size_t)(bm + row) * KAPP + k];
                v = pack8(*reinterpret_cast<const f32x4*>(p),
                          *reinterpret_cast<const f32x4*>(p + 4));
            }
            ra = v;
        }
        #pragma unroll
        for (int i = 0; i < 4; ++i) {
            int c = tid + (i << 8);
            int n = c >> 2, ko = (c & 3) << 3;
            rb[i] = *reinterpret_cast<const u16x8*>(&Bp[(size_t)n * KPAD + kt + ko]);
        }
    };
    auto swrite = [&](int b) {
        {
            int row = tid >> 2, ko = (tid & 3) << 3;
            *reinterpret_cast<u16x8*>(&As[b][row * LDP + ko]) = ra;
        }
        #pragma unroll
        for (int i = 0; i < 4; ++i) {
            int c = tid + (i << 8);
            int n = c >> 2, ko = (c & 3) << 3;
            *reinterpret_cast<u16x8*>(&Bs[b][n * LDP + ko]) = rb[i];
        }
    };

    f32x4 zero = {0.f, 0.f, 0.f, 0.f};
    f32x4 acc[4][4];
    #pragma unroll
    for (int i = 0; i < 4; ++i)
        #pragma unroll
        for (int j = 0; j < 4; ++j) acc[i][j] = zero;

    constexpr int NS = 79;               // 2528 / 32
    gload(k0); swrite(0); __syncthreads();
    for (int s = 0; s < NS; ++s) {
        int cur = s & 1;
        if (s + 1 < NS) gload(k0 + ((s + 1) << 5));
        const int kh8 = (lane >> 4) << 3, rl = lane & 15;
        bf16x8 af[4], bfr[4];
        #pragma unroll
        for (int i = 0; i < 4; ++i)
            af[i] = *reinterpret_cast<const bf16x8*>(&As[cur][(i * 16 + rl) * LDP + kh8]);
        #pragma unroll
        for (int j = 0; j < 4; ++j)
            bfr[j] = *reinterpret_cast<const bf16x8*>(&Bs[cur][((w << 6) + j * 16 + rl) * LDP + kh8]);
        #pragma unroll
        for (int i = 0; i < 4; ++i)
            #pragma unroll
            for (int j = 0; j < 4; ++j)
                acc[i][j] = __builtin_amdgcn_mfma_f32_16x16x32_bf16(af[i], bfr[j], acc[i][j], 0, 0, 0);
        if (s + 1 < NS) {
            __syncthreads();
            swrite(cur ^ 1);
            __syncthreads();
        }
    }
    float* P = part + ((size_t)ks * S + bm) * EAPP;
    const int rq = (lane >> 4) << 2, rl = lane & 15;
    #pragma unroll
    for (int i = 0; i < 4; ++i)
        #pragma unroll
        for (int j = 0; j < 4; ++j) {
            int col = (w << 6) + j * 16 + rl;
            #pragma unroll
            for (int q = 0; q < 4; ++q)
                P[(size_t)(i * 16 + rq + q) * EAPP + col] = acc[i][j][q];
        }
}

// ----------------------------------- reduce split-K partials -> xb[:,0:256]
__global__ __launch_bounds__(256) void k_reduce_app(
    const float* __restrict__ part, unsigned short* __restrict__ xb)
{
    int id = blockIdx.x * 256 + threadIdx.x;   // 262144 = 4096*64
    int row = id >> 6, c4 = (id & 63) << 2;
    f32x4 s = {0.f, 0.f, 0.f, 0.f};
    #pragma unroll
    for (int sl = 0; sl < 4; ++sl) {
        f32x4 v = *reinterpret_cast<const f32x4*>(
            &part[((size_t)sl * S + row) * EAPP + c4]);
        s.x += v.x; s.y += v.y; s.z += v.z; s.w += v.w;
    }
    unsigned short* o = &xb[(size_t)row * DIN + c4];
    o[0] = f2bf(s.x); o[1] = f2bf(s.y); o[2] = f2bf(s.z); o[3] = f2bf(s.w);
}

// ------------------------------------------------- attention score + pooling
__global__ __launch_bounds__(256) void k_score(
    const unsigned short* __restrict__ xb, const float* __restrict__ W,
    float* __restrict__ s)
{
    int wv = threadIdx.x >> 6, lane = threadIdx.x & 63;
    int m = blockIdx.x * 4 + wv;
    float sum = 0.f;
    #pragma unroll
    for (int i = 0; i < 5; ++i) {
        int k = lane + (i << 6);
        sum += bf2f(xb[(size_t)m * DIN + k]) * W[k];
    }
    #pragma unroll
    for (int off = 32; off; off >>= 1) sum += __shfl_down(sum, off);
    if (lane == 0) s[m] = sum;
}

__global__ void k_pooled(
    const unsigned short* __restrict__ xb, const float* __restrict__ s,
    const float* __restrict__ attn_b, unsigned short* __restrict__ pooledb)
{
    int n = blockIdx.x, d = threadIdx.x;
    float h[4], den = 0.f;
    #pragma unroll
    for (int f = 0; f < 4; ++f) {
        h[f] = tanhf(s[n + f] + attn_b[f]);
        den += fabsf(h[f]);
    }
    float inv = 1.f / den, p = 0.f;
    #pragma unroll
    for (int f = 0; f < 4; ++f)
        p = fmaf(h[f] * inv, bf2f(xb[(size_t)(n + f) * DIN + d]), p);
    pooledb[(size_t)n * DIN + d] = f2bf(p);
}

// --------------------------------------------------- NT MFMA GEMM, 128x128
// C[m,j] = epi( sum_k A[m,k]*B[j,k] ).  A bf16 [4096][K], B bf16 [Nb][K].
// EPI 1: (acc+bias[j])*uid_emb[j] -> bf16, all rows. EPI 2: sigmoid -> f32, row<Mlim.
template<int EPI>
__global__ __launch_bounds__(256) void k_gemm_nt_mfma(
    const unsigned short* __restrict__ A, const unsigned short* __restrict__ B,
    int Nb, int K, int Mlim,
    const float* __restrict__ bias,
    const float* __restrict__ emb_uid, const int* __restrict__ uid,
    void* __restrict__ Cout, int ldc)
{
    __shared__ unsigned short As[2][128 * LDP];
    __shared__ unsigned short Bs[2][128 * LDP];
    const int tid = threadIdx.x;
    const int lane = tid & 63, w = tid >> 6;
    const int bn = blockIdx.x << 7, bm = blockIdx.y << 7;
    const int wr = (w >> 1) << 6, wc = (w & 1) << 6;

    u16x8 ra[2], rb[2];
    auto gload = [&](int kt) {
        #pragma unroll
        for (int i = 0; i < 2; ++i) {
            int c = tid + (i << 8);
            int row = c >> 2, ko = (c & 3) << 3;
            ra[i] = *reinterpret_cast<const u16x8*>(&A[(size_t)(bm + row) * K + kt + ko]);
            int brow = bn + row;
            u16x8 z = {0,0,0,0,0,0,0,0};
            rb[i] = (brow < Nb)
                ? *reinterpret_cast<const u16x8*>(&B[(size_t)brow * K + kt + ko]) : z;
        }
    };
    auto swrite = [&](int b) {
        #pragma unroll
        for (int i = 0; i < 2; ++i) {
            int c = tid + (i << 8);
            int row = c >> 2, ko = (c & 3) << 3;
            *reinterpret_cast<u16x8*>(&As[b][row * LDP + ko]) = ra[i];
            *reinterpret_cast<u16x8*>(&Bs[b][row * LDP + ko]) = rb[i];
        }
    };

    f32x4 zero = {0.f, 0.f, 0.f, 0.f};
    f32x4 acc[4][4];
    #pragma unroll
    for (int i = 0; i < 4; ++i)
        #pragma unroll
        for (int j = 0; j < 4; ++j) acc[i][j] = zero;

    const int NS = K >> 5;
    gload(0); swrite(0); __syncthreads();
    for (int s = 0; s < NS; ++s) {
        int cur = s & 1;
        if (s + 1 < NS) gload((s + 1) << 5);
        const int kh8 = (lane >> 4) << 3, rl = lane & 15;
        bf16x8 af[4], bfr[4];
        #pragma unroll
        for (int i = 0; i < 4; ++i)
            af[i] = *reinterpret_cast<const bf16x8*>(&As[cur][(wr + i * 16 + rl) * LDP + kh8]);
        #pragma unroll
        for (int j = 0; j < 4; ++j)
            bfr[j] = *reinterpret_cast<const bf16x8*>(&Bs[cur][(wc + j * 16 + rl) * LDP + kh8]);
        #pragma unroll
        for (int i = 0; i < 4; ++i)
            #pragma unroll
            for (int j = 0; j < 4; ++j)
                acc[i][j] = __builtin_amdgcn_mfma_f32_16x16x32_bf16(af[i], bfr[j], acc[i][j], 0, 0, 0);
        if (s + 1 < NS) {
            __syncthreads();
            swrite(cur ^ 1);
            __syncthreads();
        }
    }

    const int rq = (lane >> 4) << 2, rl = lane & 15;
    if (EPI == 1) {
        unsigned short* C = (unsigned short*)Cout;
        const float* us = emb_uid + (size_t)uid[0] * EAPP;
        #pragma unroll
        for (int j = 0; j < 4; ++j) {
            int col = bn + wc + j * 16 + rl;
            float um = us[col], bb = bias[col];
            #pragma unroll
            for (int i = 0; i < 4; ++i)
                #pragma unroll
                for (int q = 0; q < 4; ++q) {
                    int row = bm + wr + i * 16 + rq + q;
                    C[(size_t)row * ldc + col] = f2bf((acc[i][j][q] + bb) * um);
                }
        }
    } else {
        float* C = (float*)Cout;
        #pragma unroll
        for (int j = 0; j < 4; ++j) {
            int col = bn + wc + j * 16 + rl;
            if (col >= Nb) continue;
            float bb = bias[col];
            #pragma unroll
            for (int i = 0; i < 4; ++i)
                #pragma unroll
                for (int q = 0; q < 4; ++q) {
                    int row = bm + wr + i * 16 + rq + q;
                    if (row < Mlim) {
                        float v = acc[i][j][q] + bb;
                        C[(size_t)row * ldc + col] = 1.f / (1.f + __expf(-v));
                    }
                }
        }
    }
}

// ---------------------------------------------------------------- launcher
extern "C" void kernel_launch(void* const* d_in, const int* in_sizes, int n_in,
                              void* d_out, int out_size, void* d_ws, size_t ws_size,
                              hipStream_t stream)
{
    const int*   tim       = (const int*)  d_in[0];
    const float* app       = (const float*)d_in[1];
    const int*   uid       = (const int*)  d_in[3];
    const int*   ptim      = (const int*)  d_in[4];
    const float* emb_tim_w = (const float*)d_in[5];
    const float* emb_uid_w = (const float*)d_in[6];
    const float* emb_app_w = (const float*)d_in[7];
    const float* attn_W    = (const float*)d_in[8];
    const float* attn_b    = (const float*)d_in[9];
    const float* attn_fc_w = (const float*)d_in[10];
    const float* attn_fc_b = (const float*)d_in[11];
    const float* dec_w     = (const float*)d_in[12];
    const float* dec_b     = (const float*)d_in[13];
    float* out = (float*)d_out;

    char* w = (char*)d_ws;
    size_t o = 0;
    auto alloc = [&](size_t bytes) { char* p = w + o; o = (o + bytes + 511) & ~(size_t)511; return p; };
    unsigned short* xb      = (unsigned short*)alloc((size_t)S * DIN * 2);
    unsigned short* pooledb = (unsigned short*)alloc((size_t)S * DIN * 2);
    unsigned short* yb      = (unsigned short*)alloc((size_t)S * DIN * 2);
    float*          s       = (float*)        alloc((size_t)S * 4);
    unsigned short* Bp      = (unsigned short*)alloc((size_t)EAPP * KPAD * 2);
    unsigned short* decb    = (unsigned short*)alloc((size_t)NDEC * DIN * 2);
    unsigned short* fcb     = (unsigned short*)alloc((size_t)EAPP * DIN * 2);
    float*          part    = (float*)        alloc((size_t)4 * S * EAPP * 4);

    // weight conversions (independent)
    k_cvt_bf16<<<(NDEC * DIN / 8 + 255) / 256, 256, 0, stream>>>(dec_w, decb, NDEC * DIN / 8);
    k_cvt_bf16<<<(EAPP * DIN / 8 + 255) / 256, 256, 0, stream>>>(attn_fc_w, fcb, EAPP * DIN / 8);
    dim3 gT(KPAD / 64, EAPP / 64);
    k_transpose_appw<<<gT, 256, 0, stream>>>(emb_app_w, Bp);
    k_embed_tim<<<S / 4, 256, 0, stream>>>(tim, emb_tim_w, xb);

    // x[:,0:256] = app @ emb_app_w   (split-K MFMA + reduce)
    dim3 gApp(4, S / 64);
    k_gemm_app_mfma<<<gApp, 256, 0, stream>>>(app, Bp, part);
    k_reduce_app<<<S * 64 / 256, 256, 0, stream>>>(part, xb);

    // attention
    k_score<<<S / 4, 256, 0, stream>>>(xb, attn_W, s);
    k_pooled<<<NR, DIN, 0, stream>>>(xb, s, attn_b, pooledb);
    k_embed_ptim<<<S / 4, 256, 0, stream>>>(ptim, emb_tim_w, yb);

    // y[:,0:256] = (pooled @ fc^T + b) * uid_emb   (bf16 out)
    dim3 gFc(EAPP / 128, S / 128);
    k_gemm_nt_mfma<1><<<gFc, 256, 0, stream>>>(pooledb, fcb, EAPP, DIN, S,
                                               attn_fc_b, emb_uid_w, uid, yb, DIN);
    // score = sigmoid(y @ dec_w^T + dec_b)
    dim3 gDec((NDEC + 127) / 128, S / 128);
    k_gemm_nt_mfma<2><<<gDec, 256, 0, stream>>>(yb, decb, NDEC, DIN, NR,
                                                dec_b, nullptr, nullptr, out, NDEC);
}